// Round 5
// baseline (226.187 us; speedup 1.0000x reference)
//
#include <hip/hip_runtime.h>

#define H 64
#define NEDGE 50000
#define NNODE 12000
#define EPAD 50176

typedef _Float16 f16;
typedef _Float16 h8 __attribute__((ext_vector_type(8)));
typedef float f4 __attribute__((ext_vector_type(4)));
typedef float fv16 __attribute__((ext_vector_type(16)));

// workspace layout (bytes)
#define O_EDGEH 0ull            // edge f16 padded [50176][64]        = 6,422,528
#define O_W2G   6422528ull      // swizzled W2 f16 (64 chunks x 16KB) = 1,048,576
#define O_B2G   7471104ull      // swizzled b2 f16 (K=64 chunk, 8KB)  — MUST follow w2g (tail reads w2g+64*8192)
#define O_W1G   7479296ull      // swizzled W1 f16 (16KB)
#define O_WG    7495680ull      // GRU combined weights f16 (64KB)
#define O_AGG   7561216ull      // agg f32 [12000][64]                = 3,072,000

__device__ __forceinline__ void async16(const void* g, void* l) {
  __builtin_amdgcn_global_load_lds((const __attribute__((address_space(1))) void*)g,
                                   (__attribute__((address_space(3))) void*)l, 16, 0, 0);
}

__device__ __forceinline__ fv16 zero16() {
  fv16 z;
#pragma unroll
  for (int i = 0; i < 16; ++i) z[i] = 0.f;
  return z;
}

// ---------------- prep: agg zero, edge->f16, W2/b2/W1/Wgru -> 32x32x16 MFMA-B granule order
// w2g: chunk h in [0,64); granule g=(s*2+nh)*64+l, elem i: W2[(h*64 + nh*32+(l&31))*128 + s*16+((l>>5)<<3)+i]
// b2g: granule g=(s*2+nh)*64+l (s<4), elem i: b2[(s*16+((l>>5)<<3)+i)*64 + nh*32+(l&31)]
// w1g: granule g=(s*4+nt)*64+l (s<4,nt<4), elem i: W1[(nt*32+(l&31))*64 + s*16+((l>>5)<<3)+i]
__global__ __launch_bounds__(256) void k_prep(const float* __restrict__ edge, const float* __restrict__ W1,
                                              const float* __restrict__ W2, const float* __restrict__ b2,
                                              const float* __restrict__ Wih, const float* __restrict__ Whh,
                                              f16* __restrict__ edgeh, f16* __restrict__ w1g, f16* __restrict__ w2g,
                                              f16* __restrict__ b2g, f16* __restrict__ wg, float* __restrict__ agg) {
  int bid = blockIdx.x;
  int t = threadIdx.x;
  if (bid < 750) {  // agg zero
    int id = bid * 256 + t;
    *(f4*)(agg + (long)id * 4) = (f4){0.f, 0.f, 0.f, 0.f};
    return;
  }
  if (bid < 2318) {  // edgeh cast, 8 elems/thread (EPAD rows, pad zeroed)
    long id8 = (long)(bid - 750) * 256 + t;
    long e = id8 >> 3;
    int c = (int)(id8 & 7) * 8;
    h8 o = {};
    if (e < NEDGE) {
      const float* p = edge + e * 64 + c;
      f4 v0 = *(const f4*)p, v1 = *(const f4*)(p + 4);
#pragma unroll
      for (int j = 0; j < 4; ++j) { o[j] = (f16)v0[j]; o[4 + j] = (f16)v1[j]; }
    }
    *(h8*)(edgeh + e * 64 + c) = o;
    return;
  }
  if (bid < 4366) {  // w2g: 524288 f16
    int id = (bid - 2318) * 256 + t;
    int i = id & 7, l = (id >> 3) & 63, nh = (id >> 9) & 1, s = (id >> 10) & 7, h = id >> 13;
    int n = nh * 32 + (l & 31), j = s * 16 + ((l >> 5) << 3) + i;
    w2g[id] = (f16)W2[(h * 64 + n) * 128 + j];
    return;
  }
  if (bid < 4382) {  // b2g: 4096 f16
    int id = (bid - 4366) * 256 + t;
    int i = id & 7, l = (id >> 3) & 63, nh = (id >> 9) & 1, s = id >> 10;
    int n = nh * 32 + (l & 31), k = s * 16 + ((l >> 5) << 3) + i;
    b2g[id] = (f16)b2[k * 64 + n];
    return;
  }
  if (bid < 4414) {  // w1g: 8192 f16
    int id = (bid - 4382) * 256 + t;
    int i = id & 7, l = (id >> 3) & 63, nt = (id >> 9) & 3, s = id >> 11;
    int n = nt * 32 + (l & 31), k = s * 16 + ((l >> 5) << 3) + i;
    w1g[id] = (f16)W1[n * 64 + k];
    return;
  }
  // wg: GRU combined B matrix [128k][256n] in 16x16x32 granule order, 32768 f16
  {
    int id = (bid - 4414) * 256 + t;
    int ii = id & 7, l = (id >> 3) & 63, tt = (id >> 9) & 15, s = id >> 13;
    int k = s * 32 + ((l >> 4) << 3) + ii, n = tt * 16 + (l & 15);
    float v;
    if (n < 128) v = (k < 64) ? Wih[n * 64 + k] : Whh[n * 64 + (k - 64)];
    else if (n < 192) v = (k < 64) ? Wih[n * 64 + k] : 0.f;
    else v = (k < 64) ? 0.f : Whh[(n - 64) * 64 + (k - 64)];
    wg[id] = (f16)v;
  }
}

// ---------------- fused msg kernel v6: 128 edges/block, hs-split x2 (grid 784 -> 3 blocks/CU).
// Waves K(j)-split: kh=wave&1 owns j-half, wn=wave>>1 owns N-half; wave tile M=128, N=32, K=64/h.
// eh is h-invariant and register-resident. B per h (4KB/wave quarter) is DMA'd into a WAVE-PRIVATE
// 2-slot LDS ring via global_load_lds and read back with ds_read_b128 -- NO cross-wave sharing, so
// NO barriers in the h-loop. v5 FAILED (absmax 5.14): without barriers, hipcc emits NO vmcnt wait
// tying the DMA to the aliasing ds_read -> slot-h reads raced slot-h DMA. v6 fix: explicit inline-asm
// `s_waitcnt vmcnt(0)` before the slot reads (fenced by sched_barrier(0) so reads can't hoist above
// the wait and the h+1 DMA can't hoist above the reads). Semantically exact: at that point the ONLY
// outstanding VMEM ops are h's own 4 DMAs, issued one full compute phase (~512 MFMA-cyc) earlier vs
// ~200cyc L2 latency -> wait is ~free. Ring replaces r3's register dbuf (64 VGPR -> 16 transient):
// peak live ~160 regs, fits launch_bounds(256,3) = 3 blocks/CU, 12 waves/CU (r3 was latency-bound at
// 2 blocks/CU, MfmaUtil 25%).
__global__ __launch_bounds__(256, 3) void k_msg(const float* __restrict__ node,
                                                const int* __restrict__ src, const int* __restrict__ dst,
                                                const f16* __restrict__ edgeh, const f16* __restrict__ w1g,
                                                const f16* __restrict__ w2g, const float* __restrict__ b1,
                                                float* __restrict__ agg) {
  // [0,32768) eh_s (phases 1-2, 128 rows x 256B) / rings (h-loop: 4 waves x 8KB) / red (f32 reduction)
  // [32768,51200) vT f16 [128 e][72] (pitch 144B, granule (e,hb) = v[e][8hb..8hb+7])
  // [51200,51712) sdst | [51712,52224) b1s (128 f32)
  __shared__ __align__(16) char lds[52224];
  f16* eh_s = (f16*)lds;
  f16* vT = (f16*)(lds + 32768);
  int* sdst = (int*)(lds + 51200);
  float* b1s = (float*)(lds + 51712);

  int t = threadIdx.x;
  int bid = blockIdx.x;
  int e_base = (bid >> 1) * 128;
  int hs = bid & 1;  // h-split half: 0 -> h in [0,32), 1 -> h in [32,64) + b2 tail

  // ---- phase 0: indices, b1, v gather -> vT
  if (t < 128) {
    int eg = e_base + t;
    sdst[t] = (eg < NEDGE) ? dst[eg] : 0;
  } else {
    b1s[t - 128] = b1[t - 128];
  }
  {
    int e = t >> 1, half = t & 1;
    int eg = e_base + e;
    int si = (eg < NEDGE) ? src[eg] : 0;
    const f4* nr = (const f4*)(node + (long)si * 64 + half * 32);
#pragma unroll
    for (int b = 0; b < 4; ++b) {
      f4 v0 = nr[b * 2], v1 = nr[b * 2 + 1];
      h8 pk;
#pragma unroll
      for (int m = 0; m < 4; ++m) { pk[m] = (f16)v0[m]; pk[4 + m] = (f16)v1[m]; }
      *(h8*)(vT + e * 72 + (half * 4 + b) * 8) = pk;
    }
  }
  __syncthreads();

  int wave = t >> 6, lane = t & 63;
  int wm = wave & 1, wn = wave >> 1;  // phase-1 roles
  int l31 = lane & 31, lh = lane >> 5;
  int kh = wm;  // phase-3 role: K-half owner

  // ---- phase 1: eh = relu(edge @ W1^T + b1), M=128/N=128/K=64, wave tile 64x64
  {
    h8 afr[2][4];
#pragma unroll
    for (int mt = 0; mt < 2; ++mt)
#pragma unroll
      for (int s = 0; s < 4; ++s)
        afr[mt][s] = *(const h8*)(edgeh + (long)(e_base + wm * 64 + mt * 32 + l31) * 64 + s * 16 + lh * 8);
    h8 bfr[2][4];
#pragma unroll
    for (int nt = 0; nt < 2; ++nt)
#pragma unroll
      for (int s = 0; s < 4; ++s)
        bfr[nt][s] = *(const h8*)(w1g + ((s * 4 + wn * 2 + nt) * 64 + lane) * 8);
    fv16 acc_eh[2][2];
#pragma unroll
    for (int mt = 0; mt < 2; ++mt)
#pragma unroll
      for (int nt = 0; nt < 2; ++nt) acc_eh[mt][nt] = zero16();
#pragma unroll
    for (int s = 0; s < 4; ++s)
#pragma unroll
      for (int mt = 0; mt < 2; ++mt)
#pragma unroll
        for (int nt = 0; nt < 2; ++nt)
          acc_eh[mt][nt] = __builtin_amdgcn_mfma_f32_32x32x16_f16(afr[mt][s], bfr[nt][s], acc_eh[mt][nt], 0, 0, 0);
    // write eh tile to LDS, swizzled granules, + b1 + relu
#pragma unroll
    for (int mt = 0; mt < 2; ++mt)
#pragma unroll
      for (int nt = 0; nt < 2; ++nt)
#pragma unroll
        for (int r = 0; r < 16; ++r) {
          int row = (r & 3) + 8 * (r >> 2) + 4 * lh;
          int e = wm * 64 + mt * 32 + row;
          int n = wn * 64 + nt * 32 + l31;
          float val = fmaxf(acc_eh[mt][nt][r] + b1s[n], 0.f);
          int o = n >> 3;
          eh_s[e * 128 + ((o ^ (e & 15)) << 3) + (n & 7)] = (f16)val;
        }
  }
  __syncthreads();

  // ---- phase 2: eh fragments -> registers. Wave (kh,wn) takes ALL 128 rows x its K-half.
  h8 ehreg[4][4];
#pragma unroll
  for (int mt = 0; mt < 4; ++mt) {
    int e = mt * 32 + l31;
#pragma unroll
    for (int s = 0; s < 4; ++s) {
      int o = ((kh * 4 + s) * 2 + lh) ^ (e & 15);
      ehreg[mt][s] = *(const h8*)(eh_s + e * 128 + o * 8);
    }
  }
  __syncthreads();  // eh_s dead -> ring region free

  // ---- phase 3: 32 h iterations, B via wave-private LDS ring (2 slots x 4KB). NO barriers.
  fv16 acc[4];
#pragma unroll
  for (int mt = 0; mt < 4; ++mt) acc[mt] = zero16();
  const f16* vr0 = vT + l31 * 72;  // row mt*32+l31 -> + mt*2304 f16

  char* ring = lds + wave * 8192;              // wave-private ring, overlays eh_s (dead)
  const char* w2b = (const char*)w2g;
  // s-granule byte offset within a 16KB h-chunk for this wave: (kh*8+wn)*1024, s-stride 2048
  long gq = ((long)(kh * 8 + wn)) * 1024;
  int hfirst = hs << 5;
  int hlast = hfirst + 31;

  // prologue DMA: h=hfirst -> slot 0
#pragma unroll
  for (int s = 0; s < 4; ++s)
    async16(w2b + (long)hfirst * 16384 + gq + s * 2048 + lane * 16, ring + s * 1024 + lane * 16);

#pragma unroll 1
  for (int hb = hs * 4; hb < hs * 4 + 4; ++hb) {
    h8 vh[4];
#pragma unroll
    for (int mt = 0; mt < 4; ++mt) vh[mt] = *(const h8*)(vr0 + mt * 2304 + hb * 8);
#pragma unroll
    for (int hh = 0; hh < 8; ++hh) {
      int h = hb * 8 + hh;
      // counted wait: the only outstanding VMEM ops here are slot-h's own 4 DMAs, issued one full
      // compute phase earlier -> ~free. MANDATORY for correctness (v5 raced without it).
      __builtin_amdgcn_sched_barrier(0);
      asm volatile("s_waitcnt vmcnt(0)" ::: "memory");
      __builtin_amdgcn_sched_barrier(0);
      const f16* slot = (const f16*)(ring + (h & 1) * 4096) + lane * 8;
      h8 bf[4];
#pragma unroll
      for (int s = 0; s < 4; ++s) bf[s] = *(const h8*)(slot + s * 512);
      __builtin_amdgcn_sched_barrier(0);  // pin: h+1 DMA must not hoist above the slot-h ds_reads
      if (h != hlast) {
        const char* gsrc = w2b + (long)(h + 1) * 16384 + gq + lane * 16;
        char* ldst = ring + ((h + 1) & 1) * 4096 + lane * 16;
#pragma unroll
        for (int s = 0; s < 4; ++s) async16(gsrc + s * 2048, ldst + s * 1024);
      }
      __builtin_amdgcn_sched_barrier(0);  // pin: compute stays after DMA issue
      f16 vcur[4];
#pragma unroll
      for (int mt = 0; mt < 4; ++mt) vcur[mt] = vh[mt][hh];
#pragma unroll
      for (int s = 0; s < 4; ++s) {
        h8 bfs = bf[s];
#pragma unroll
        for (int mt = 0; mt < 4; ++mt) {
          h8 a = ehreg[mt][s] * vcur[mt];
          acc[mt] = __builtin_amdgcn_mfma_f32_32x32x16_f16(a, bfs, acc[mt], 0, 0, 0);
        }
      }
    }
  }

  // ---- b2 bias tail (K=64 over h, kh-split s pairs): hs=1 blocks only, A = v directly (global->reg)
  if (hs) {
    const f16* bt = w2g + (long)64 * 8192 + kh * 2048 + wn * 512 + (long)lane * 8;
#pragma unroll
    for (int sw = 0; sw < 2; ++sw) {
      h8 bf = *(const h8*)(bt + sw * 1024);
#pragma unroll
      for (int mt = 0; mt < 4; ++mt) {
        h8 a = *(const h8*)(vr0 + mt * 2304 + ((kh * 2 + sw) * 2 + lh) * 8);
        acc[mt] = __builtin_amdgcn_mfma_f32_32x32x16_f16(a, bf, acc[mt], 0, 0, 0);
      }
    }
  }

  // ---- kh-pair reduction via red (ring region, dead after loop). Wave w=(wn*2+kh) owns [w*8KB, +8KB).
  // Each wave surrenders 2 tiles to its kh-partner, keeps mt in {kh*2, kh*2+1}.
  {
    float* red = (float*)lds;
    float* mybase = red + (wn * 2 + kh) * 2048;
    auto wr = [&](const fv16& a, int sl) {
#pragma unroll
      for (int r = 0; r < 4; ++r) {
        f4 q = {a[4 * r], a[4 * r + 1], a[4 * r + 2], a[4 * r + 3]};
        *(f4*)(mybase + sl * 1024 + r * 256 + lane * 4) = q;
      }
    };
    if (!kh) { wr(acc[2], 0); wr(acc[3], 1); }
    else { wr(acc[0], 0); wr(acc[1], 1); }
    __syncthreads();
    const float* pb = red + (wn * 2 + (1 - kh)) * 2048;
    auto rd = [&](fv16& a, int sl) {
#pragma unroll
      for (int r = 0; r < 4; ++r) {
        f4 q = *(const f4*)(pb + sl * 1024 + r * 256 + lane * 4);
        a[4 * r] += q[0]; a[4 * r + 1] += q[1]; a[4 * r + 2] += q[2]; a[4 * r + 3] += q[3];
      }
    };
    if (!kh) { rd(acc[0], 0); rd(acc[1], 1); }
    else { rd(acc[2], 0); rd(acc[3], 1); }
  }

  // ---- epilogue: atomic scatter to agg[dst]. col n = wn*32 + l31; wave kh scatters mt {kh*2, kh*2+1}
  {
    int n = wn * 32 + l31;
    auto scat = [&](const fv16& a, int mt) {
#pragma unroll
      for (int r = 0; r < 16; ++r) {
        int el = mt * 32 + (r & 3) + 8 * (r >> 2) + 4 * lh;
        if (e_base + el < NEDGE) atomicAdd(&agg[(long)sdst[el] * 64 + n], a[r]);
      }
    };
    if (!kh) { scat(acc[0], 0); scat(acc[1], 1); }
    else { scat(acc[2], 2); scat(acc[3], 3); }
  }
}

// ---------------- GRU + LayerNorm via MFMA: 128 nodes/block, 4 waves M-split.
__global__ __launch_bounds__(256) void k_node(const float* __restrict__ agg, const float* __restrict__ hid,
                                              const f16* __restrict__ wg,
                                              const float* __restrict__ bih, const float* __restrict__ bhh,
                                              const float* __restrict__ gamma, const float* __restrict__ beta,
                                              float* __restrict__ out) {
  __shared__ __align__(16) f16 xh_s[128 * 136];
  __shared__ float bsum[128], bin_s[64], bhn_s[64], gam_s[64], bet_s[64];
  int t = threadIdx.x;
  int n0 = blockIdx.x * 128;

  if (t < 128) bsum[t] = bih[t] + bhh[t];
  else if (t < 192) bin_s[t - 128] = bih[t];
  else bhn_s[t - 192] = bhh[t - 64];
  if (t < 64) gam_s[t] = gamma[t];
  else if (t < 128) bet_s[t - 64] = beta[t - 64];

  {  // stage A = [relu(agg) | hid] as f16
    int m = t >> 1, half = t & 1;
    int mg = n0 + m;
    bool vld = mg < NNODE;
    const float* sp = half ? (hid + (long)mg * 64) : (agg + (long)mg * 64);
#pragma unroll
    for (int jj = 0; jj < 8; ++jj) {
      f4 v0 = {0, 0, 0, 0}, v1 = {0, 0, 0, 0};
      if (vld) { v0 = *(const f4*)(sp + jj * 8); v1 = *(const f4*)(sp + jj * 8 + 4); }
      h8 pk;
#pragma unroll
      for (int m2 = 0; m2 < 4; ++m2) {
        pk[m2] = (f16)(half ? v0[m2] : fmaxf(v0[m2], 0.f));
        pk[4 + m2] = (f16)(half ? v1[m2] : fmaxf(v1[m2], 0.f));
      }
      *(h8*)(xh_s + m * 136 + half * 64 + jj * 8) = pk;
    }
  }
  __syncthreads();

  int wave = t >> 6, lane = t & 63;
  int l15 = lane & 15, lq = lane >> 4;

  f4 acc[2][16];
#pragma unroll
  for (int g = 0; g < 2; ++g)
#pragma unroll
    for (int tt = 0; tt < 16; ++tt) acc[g][tt] = (f4){0.f, 0.f, 0.f, 0.f};

#pragma unroll
  for (int s = 0; s < 4; ++s) {
    h8 a0 = *(const h8*)(xh_s + (wave * 32 + l15) * 136 + s * 32 + lq * 8);
    h8 a1 = *(const h8*)(xh_s + (wave * 32 + 16 + l15) * 136 + s * 32 + lq * 8);
#pragma unroll
    for (int tt = 0; tt < 16; ++tt) {
      h8 b = *(const h8*)(wg + ((s * 16 + tt) * 64 + lane) * 8);
      acc[0][tt] = __builtin_amdgcn_mfma_f32_16x16x32_f16(a0, b, acc[0][tt], 0, 0, 0);
      acc[1][tt] = __builtin_amdgcn_mfma_f32_16x16x32_f16(a1, b, acc[1][tt], 0, 0, 0);
    }
  }

#pragma unroll
  for (int g = 0; g < 2; ++g)
#pragma unroll
    for (int r = 0; r < 4; ++r) {
      int mg = n0 + wave * 32 + g * 16 + lq * 4 + r;
      bool vld = mg < NNODE;
      float o[4], ssum = 0.f, s2 = 0.f;
#pragma unroll
      for (int t0 = 0; t0 < 4; ++t0) {
        int f = t0 * 16 + l15;
        float rpre = acc[g][t0][r] + bsum[f];
        float zpre = acc[g][4 + t0][r] + bsum[64 + f];
        float ginv = acc[g][8 + t0][r] + bin_s[f];
        float ghnv = acc[g][12 + t0][r] + bhn_s[f];
        float rr = 1.f / (1.f + __expf(-rpre));
        float zz = 1.f / (1.f + __expf(-zpre));
        float hv = vld ? hid[(long)mg * 64 + f] : 0.f;
        float nn = tanhf(ginv + rr * ghnv);
        float oo = (1.f - zz) * nn + zz * hv;
        o[t0] = oo; ssum += oo; s2 += oo * oo;
      }
#pragma unroll
      for (int d = 1; d < 16; d <<= 1) {
        ssum += __shfl_xor(ssum, d);
        s2 += __shfl_xor(s2, d);
      }
      float mu = ssum * (1.f / 64.f);
      float var = s2 * (1.f / 64.f) - mu * mu;
      float rstd = rsqrtf(var + 1e-5f);
      if (vld)
#pragma unroll
        for (int t0 = 0; t0 < 4; ++t0) {
          int f = t0 * 16 + l15;
          out[(long)mg * 64 + f] = (o[t0] - mu) * rstd * gam_s[f] + bet_s[f];
        }
    }
}

extern "C" void kernel_launch(void* const* d_in, const int* in_sizes, int n_in,
                              void* d_out, int out_size, void* d_ws, size_t ws_size,
                              hipStream_t stream) {
  const float* node = (const float*)d_in[0];
  const float* edge = (const float*)d_in[1];
  const float* hid = (const float*)d_in[2];
  const int* src = (const int*)d_in[3];
  const int* dst = (const int*)d_in[4];
  const float* W1 = (const float*)d_in[5];
  const float* b1 = (const float*)d_in[6];
  const float* W2 = (const float*)d_in[7];
  const float* b2 = (const float*)d_in[8];
  const float* Wih = (const float*)d_in[9];
  const float* Whh = (const float*)d_in[10];
  const float* bih = (const float*)d_in[11];
  const float* bhh = (const float*)d_in[12];
  const float* gamma = (const float*)d_in[13];
  const float* beta = (const float*)d_in[14];

  char* ws = (char*)d_ws;
  f16* edgeh = (f16*)(ws + O_EDGEH);
  f16* w2g = (f16*)(ws + O_W2G);
  f16* b2g = (f16*)(ws + O_B2G);
  f16* w1g = (f16*)(ws + O_W1G);
  f16* wg = (f16*)(ws + O_WG);
  float* agg = (float*)(ws + O_AGG);

  k_prep<<<4542, 256, 0, stream>>>(edge, W1, W2, b2, Wih, Whh, edgeh, w1g, w2g, b2g, wg, agg);
  k_msg<<<784, 256, 0, stream>>>(node, src, dst, edgeh, w1g, w2g, b1, agg);
  k_node<<<94, 256, 0, stream>>>(agg, hid, wg, bih, bhh, gamma, beta, (float*)d_out);
}

// Round 6
// 188.818 us; speedup vs baseline: 1.1979x; 1.1979x over previous
//
#include <hip/hip_runtime.h>

#define H 64
#define NEDGE 50000
#define NNODE 12000
#define EPAD 50176

typedef _Float16 f16;
typedef _Float16 h8 __attribute__((ext_vector_type(8)));
typedef float f4 __attribute__((ext_vector_type(4)));
typedef float fv16 __attribute__((ext_vector_type(16)));

// workspace layout (bytes)
#define O_EDGEH 0ull            // edge f16 padded [50176][64]        = 6,422,528
#define O_W2G   6422528ull      // swizzled W2 f16 (64 chunks x 16KB) = 1,048,576
#define O_B2G   7471104ull      // swizzled b2 f16 (K=64 chunk, 8KB)  — MUST follow w2g (tail reads w2g+64*8192)
#define O_W1G   7479296ull      // swizzled W1 f16 (16KB)
#define O_WG    7495680ull      // GRU combined weights f16 (64KB)
#define O_AGG   7561216ull      // agg f32 [12000][64]                = 3,072,000

__device__ __forceinline__ fv16 zero16() {
  fv16 z;
#pragma unroll
  for (int i = 0; i < 16; ++i) z[i] = 0.f;
  return z;
}

// ---------------- prep: agg zero, edge->f16, W2/b2/W1/Wgru -> 32x32x16 MFMA-B granule order
// w2g: chunk h in [0,64); granule g=(s*2+nh)*64+l, elem i: W2[(h*64 + nh*32+(l&31))*128 + s*16+((l>>5)<<3)+i]
// b2g: granule g=(s*2+nh)*64+l (s<4), elem i: b2[(s*16+((l>>5)<<3)+i)*64 + nh*32+(l&31)]
// w1g: granule g=(s*4+nt)*64+l (s<4,nt<4), elem i: W1[(nt*32+(l&31))*64 + s*16+((l>>5)<<3)+i]
__global__ __launch_bounds__(256) void k_prep(const float* __restrict__ edge, const float* __restrict__ W1,
                                              const float* __restrict__ W2, const float* __restrict__ b2,
                                              const float* __restrict__ Wih, const float* __restrict__ Whh,
                                              f16* __restrict__ edgeh, f16* __restrict__ w1g, f16* __restrict__ w2g,
                                              f16* __restrict__ b2g, f16* __restrict__ wg, float* __restrict__ agg) {
  int bid = blockIdx.x;
  int t = threadIdx.x;
  if (bid < 750) {  // agg zero
    int id = bid * 256 + t;
    *(f4*)(agg + (long)id * 4) = (f4){0.f, 0.f, 0.f, 0.f};
    return;
  }
  if (bid < 2318) {  // edgeh cast, 8 elems/thread (EPAD rows, pad zeroed)
    long id8 = (long)(bid - 750) * 256 + t;
    long e = id8 >> 3;
    int c = (int)(id8 & 7) * 8;
    h8 o = {};
    if (e < NEDGE) {
      const float* p = edge + e * 64 + c;
      f4 v0 = *(const f4*)p, v1 = *(const f4*)(p + 4);
#pragma unroll
      for (int j = 0; j < 4; ++j) { o[j] = (f16)v0[j]; o[4 + j] = (f16)v1[j]; }
    }
    *(h8*)(edgeh + e * 64 + c) = o;
    return;
  }
  if (bid < 4366) {  // w2g: 524288 f16
    int id = (bid - 2318) * 256 + t;
    int i = id & 7, l = (id >> 3) & 63, nh = (id >> 9) & 1, s = (id >> 10) & 7, h = id >> 13;
    int n = nh * 32 + (l & 31), j = s * 16 + ((l >> 5) << 3) + i;
    w2g[id] = (f16)W2[(h * 64 + n) * 128 + j];
    return;
  }
  if (bid < 4382) {  // b2g: 4096 f16
    int id = (bid - 4366) * 256 + t;
    int i = id & 7, l = (id >> 3) & 63, nh = (id >> 9) & 1, s = id >> 10;
    int n = nh * 32 + (l & 31), k = s * 16 + ((l >> 5) << 3) + i;
    b2g[id] = (f16)b2[k * 64 + n];
    return;
  }
  if (bid < 4414) {  // w1g: 8192 f16
    int id = (bid - 4382) * 256 + t;
    int i = id & 7, l = (id >> 3) & 63, nt = (id >> 9) & 3, s = id >> 11;
    int n = nt * 32 + (l & 31), k = s * 16 + ((l >> 5) << 3) + i;
    w1g[id] = (f16)W1[n * 64 + k];
    return;
  }
  // wg: GRU combined B matrix [128k][256n] in 16x16x32 granule order, 32768 f16
  {
    int id = (bid - 4414) * 256 + t;
    int ii = id & 7, l = (id >> 3) & 63, tt = (id >> 9) & 15, s = id >> 13;
    int k = s * 32 + ((l >> 4) << 3) + ii, n = tt * 16 + (l & 15);
    float v;
    if (n < 128) v = (k < 64) ? Wih[n * 64 + k] : Whh[n * 64 + (k - 64)];
    else if (n < 192) v = (k < 64) ? Wih[n * 64 + k] : 0.f;
    else v = (k < 64) ? 0.f : Whh[(n - 64) * 64 + (k - 64)];
    wg[id] = (f16)v;
  }
}

// ---------------- fused msg kernel v7: 64 edges/block, hs-split x2 (grid 1564).
// Lesson ledger: r1: B-through-LDS costs 48KB LDS/block-h vs 512 MFMA-cyc -> LDS-port-capped ~35%.
//   r3: B L2->reg dbuf is right, but M=128/wave working set (~190 reg) only fits (256,2) -> 2 wv/SIMD,
//   latency-starved, 25%. r5: same set at (256,3) spills (FETCH/WRITE +146MB scratch).
// v7: QUARTER the wave tile. 4 waves = (wn,kh): each M=64 (whole block), N=32-half, K j-half.
//   Regs: ehreg[2][4]=32 + acc[2]=32 + bA/bB dbuf=32 + vh=8 + addr ~= 110 -> fits (256,3) budget 170
//   with huge margin (no spill possible); if allocator lands <=128, 4 blocks/CU for free.
//   No LDS, no barriers, no inline asm in the h-loop: plain compiler-managed register double-buffer
//   (compiler inserts correct counted vmcnt for reg loads -- r3 proved correctness of this path).
//   L2 B-read doubles (B/block is tile-invariant): ~780MB total ~= 26TB/s at 30us, under 34.5 ceiling.
__global__ __launch_bounds__(256, 3) void k_msg(const float* __restrict__ node,
                                                const int* __restrict__ src, const int* __restrict__ dst,
                                                const f16* __restrict__ edgeh, const f16* __restrict__ w1g,
                                                const f16* __restrict__ w2g, const float* __restrict__ b1,
                                                float* __restrict__ agg) {
  // [0,16384) eh_s (phases 1-2, 64 rows x 256B) / red (f32 kh-exchange, 4 x 4KB)
  // [16384,25600) vT f16 [64 e][72] (pitch 144B)
  // [25600,25856) sdst (64 int) | [25856,26368) b1s (128 f32)
  __shared__ __align__(16) char lds[26368];
  f16* eh_s = (f16*)lds;
  f16* vT = (f16*)(lds + 16384);
  int* sdst = (int*)(lds + 25600);
  float* b1s = (float*)(lds + 25856);

  int t = threadIdx.x;
  int bid = blockIdx.x;
  int e_base = (bid >> 1) * 64;
  int hs = bid & 1;  // h-split half: 0 -> h in [0,32), 1 -> h in [32,64) + b2 tail

  // ---- phase 0: indices, b1, v gather -> vT (4 threads/row, 16 f32 each)
  if (t < 64) {
    int eg = e_base + t;
    sdst[t] = (eg < NEDGE) ? dst[eg] : 0;
  } else if (t < 192) {
    b1s[t - 64] = b1[t - 64];
  }
  {
    int m = t >> 2, q = t & 3;
    int eg = e_base + m;
    int si = (eg < NEDGE) ? src[eg] : 0;
    const f4* nr = (const f4*)(node + (long)si * 64 + q * 16);
    f4 v0 = nr[0], v1 = nr[1], v2 = nr[2], v3 = nr[3];
    h8 p0, p1;
#pragma unroll
    for (int j = 0; j < 4; ++j) {
      p0[j] = (f16)v0[j]; p0[4 + j] = (f16)v1[j];
      p1[j] = (f16)v2[j]; p1[4 + j] = (f16)v3[j];
    }
    *(h8*)(vT + m * 72 + q * 16) = p0;
    *(h8*)(vT + m * 72 + q * 16 + 8) = p1;
  }
  __syncthreads();

  int wave = t >> 6, lane = t & 63;
  int l31 = lane & 31, lh = lane >> 5;
  int kh = wave & 1, wn = wave >> 1;  // phase-3 roles

  // ---- phase 1: eh = relu(edge @ W1^T + b1), M=64/N=128/K=64; wave covers N-block wave*32
  {
    h8 afr[2][4];
#pragma unroll
    for (int mt = 0; mt < 2; ++mt)
#pragma unroll
      for (int s = 0; s < 4; ++s)
        afr[mt][s] = *(const h8*)(edgeh + (long)(e_base + mt * 32 + l31) * 64 + s * 16 + lh * 8);
    h8 bfr[4];
#pragma unroll
    for (int s = 0; s < 4; ++s)
      bfr[s] = *(const h8*)(w1g + ((s * 4 + wave) * 64 + lane) * 8);
    fv16 acc_eh[2];
    acc_eh[0] = zero16(); acc_eh[1] = zero16();
#pragma unroll
    for (int s = 0; s < 4; ++s)
#pragma unroll
      for (int mt = 0; mt < 2; ++mt)
        acc_eh[mt] = __builtin_amdgcn_mfma_f32_32x32x16_f16(afr[mt][s], bfr[s], acc_eh[mt], 0, 0, 0);
    // write eh tile to LDS, swizzled granules, + b1 + relu
#pragma unroll
    for (int mt = 0; mt < 2; ++mt)
#pragma unroll
      for (int r = 0; r < 16; ++r) {
        int row = (r & 3) + 8 * (r >> 2) + 4 * lh;
        int e = mt * 32 + row;
        int n = wave * 32 + l31;
        float val = fmaxf(acc_eh[mt][r] + b1s[n], 0.f);
        int o = n >> 3;
        eh_s[e * 128 + ((o ^ (e & 15)) << 3) + (n & 7)] = (f16)val;
      }
  }
  __syncthreads();

  // ---- phase 2: eh fragments -> registers. Wave (kh,wn): all 64 rows x K j-half kh.
  h8 ehreg[2][4];
#pragma unroll
  for (int mt = 0; mt < 2; ++mt) {
    int e = mt * 32 + l31;
#pragma unroll
    for (int s = 0; s < 4; ++s) {
      int o = ((kh * 4 + s) * 2 + lh) ^ (e & 15);
      ehreg[mt][s] = *(const h8*)(eh_s + e * 128 + o * 8);
    }
  }
  __syncthreads();  // all eh_s reads retired before any wave's later red writes

  // ---- phase 3: 32 h iterations, B from L2 into registers, double-buffered. NO barriers, NO LDS.
  fv16 acc[2];
  acc[0] = zero16(); acc[1] = zero16();
  const f16* vrow = vT + l31 * 72;  // row mt*32+l31 -> + mt*32*72

  // B granule (f16): h*8192 + kh*4096 + s*1024 + wn*512 + lane*8
  const f16* bb = w2g + kh * 4096 + wn * 512 + (long)lane * 8;
  int hfirst = hs << 5;
  int hlast = hfirst + 31;

  h8 bA[4], bB[4];
#pragma unroll
  for (int s = 0; s < 4; ++s) bA[s] = *(const h8*)(bb + (long)hfirst * 8192 + s * 1024);

  auto step = [&](h8 (&bc)[4], h8 (&bn)[4], int h, f16 v0, f16 v1) {
    if (h < hlast) {
      const f16* bp = bb + (long)(h + 1) * 8192;
#pragma unroll
      for (int s = 0; s < 4; ++s) bn[s] = *(const h8*)(bp + s * 1024);
    }
#pragma unroll
    for (int s = 0; s < 4; ++s) {
      h8 bf = bc[s];
      h8 a0 = ehreg[0][s] * v0;
      acc[0] = __builtin_amdgcn_mfma_f32_32x32x16_f16(a0, bf, acc[0], 0, 0, 0);
      h8 a1 = ehreg[1][s] * v1;
      acc[1] = __builtin_amdgcn_mfma_f32_32x32x16_f16(a1, bf, acc[1], 0, 0, 0);
    }
  };

#pragma unroll 1
  for (int hb = hs * 4; hb < hs * 4 + 4; ++hb) {
    h8 vh0 = *(const h8*)(vrow + hb * 8);
    h8 vh1 = *(const h8*)(vrow + 32 * 72 + hb * 8);
#pragma unroll
    for (int hh = 0; hh < 8; ++hh) {
      int h = hb * 8 + hh;
      if (hh & 1) step(bB, bA, h, vh0[hh], vh1[hh]);
      else step(bA, bB, h, vh0[hh], vh1[hh]);
    }
  }

  // ---- b2 bias tail (K=64 over h, kh-split s pairs): hs=1 blocks only, A = v from vT (still live)
  if (hs) {
    const f16* bt = w2g + (long)64 * 8192 + kh * 2048 + wn * 512 + (long)lane * 8;
#pragma unroll
    for (int sw = 0; sw < 2; ++sw) {
      h8 bf = *(const h8*)(bt + sw * 1024);
#pragma unroll
      for (int mt = 0; mt < 2; ++mt) {
        h8 a = *(const h8*)(vrow + mt * 32 * 72 + ((kh * 2 + sw) * 2 + lh) * 8);
        acc[mt] = __builtin_amdgcn_mfma_f32_32x32x16_f16(a, bf, acc[mt], 0, 0, 0);
      }
    }
  }

  // ---- kh-pair exchange via red (eh_s region, dead). Wave w=wn*2+kh owns [w*4KB, +4KB);
  // keeps mt=kh (rows kh*32..), surrenders mt=1-kh to partner w^1.
  {
    float* red = (float*)lds;
    float* mybase = red + wave * 1024;
    auto wr = [&](const fv16& a) {
#pragma unroll
      for (int r = 0; r < 4; ++r) {
        f4 q = {a[4 * r], a[4 * r + 1], a[4 * r + 2], a[4 * r + 3]};
        *(f4*)(mybase + r * 256 + lane * 4) = q;
      }
    };
    if (!kh) wr(acc[1]); else wr(acc[0]);
    __syncthreads();
    const float* pb = red + (wave ^ 1) * 1024;
    auto rd = [&](fv16& a) {
#pragma unroll
      for (int r = 0; r < 4; ++r) {
        f4 q = *(const f4*)(pb + r * 256 + lane * 4);
        a[4 * r] += q[0]; a[4 * r + 1] += q[1]; a[4 * r + 2] += q[2]; a[4 * r + 3] += q[3];
      }
    };
    if (!kh) rd(acc[0]); else rd(acc[1]);
  }

  // ---- epilogue: atomic scatter. Wave scatters rows kh*32+crow, col n = wn*32+l31.
  {
    int n = wn * 32 + l31;
    const fv16& a = kh ? acc[1] : acc[0];
#pragma unroll
    for (int r = 0; r < 16; ++r) {
      int el = kh * 32 + (r & 3) + 8 * (r >> 2) + 4 * lh;
      if (e_base + el < NEDGE) atomicAdd(&agg[(long)sdst[el] * 64 + n], a[r]);
    }
  }
}

// ---------------- GRU + LayerNorm via MFMA: 128 nodes/block, 4 waves M-split.
__global__ __launch_bounds__(256) void k_node(const float* __restrict__ agg, const float* __restrict__ hid,
                                              const f16* __restrict__ wg,
                                              const float* __restrict__ bih, const float* __restrict__ bhh,
                                              const float* __restrict__ gamma, const float* __restrict__ beta,
                                              float* __restrict__ out) {
  __shared__ __align__(16) f16 xh_s[128 * 136];
  __shared__ float bsum[128], bin_s[64], bhn_s[64], gam_s[64], bet_s[64];
  int t = threadIdx.x;
  int n0 = blockIdx.x * 128;

  if (t < 128) bsum[t] = bih[t] + bhh[t];
  else if (t < 192) bin_s[t - 128] = bih[t];
  else bhn_s[t - 192] = bhh[t - 64];
  if (t < 64) gam_s[t] = gamma[t];
  else if (t < 128) bet_s[t - 64] = beta[t - 64];

  {  // stage A = [relu(agg) | hid] as f16
    int m = t >> 1, half = t & 1;
    int mg = n0 + m;
    bool vld = mg < NNODE;
    const float* sp = half ? (hid + (long)mg * 64) : (agg + (long)mg * 64);
#pragma unroll
    for (int jj = 0; jj < 8; ++jj) {
      f4 v0 = {0, 0, 0, 0}, v1 = {0, 0, 0, 0};
      if (vld) { v0 = *(const f4*)(sp + jj * 8); v1 = *(const f4*)(sp + jj * 8 + 4); }
      h8 pk;
#pragma unroll
      for (int m2 = 0; m2 < 4; ++m2) {
        pk[m2] = (f16)(half ? v0[m2] : fmaxf(v0[m2], 0.f));
        pk[4 + m2] = (f16)(half ? v1[m2] : fmaxf(v1[m2], 0.f));
      }
      *(h8*)(xh_s + m * 136 + half * 64 + jj * 8) = pk;
    }
  }
  __syncthreads();

  int wave = t >> 6, lane = t & 63;
  int l15 = lane & 15, lq = lane >> 4;

  f4 acc[2][16];
#pragma unroll
  for (int g = 0; g < 2; ++g)
#pragma unroll
    for (int tt = 0; tt < 16; ++tt) acc[g][tt] = (f4){0.f, 0.f, 0.f, 0.f};

#pragma unroll
  for (int s = 0; s < 4; ++s) {
    h8 a0 = *(const h8*)(xh_s + (wave * 32 + l15) * 136 + s * 32 + lq * 8);
    h8 a1 = *(const h8*)(xh_s + (wave * 32 + 16 + l15) * 136 + s * 32 + lq * 8);
#pragma unroll
    for (int tt = 0; tt < 16; ++tt) {
      h8 b = *(const h8*)(wg + ((s * 16 + tt) * 64 + lane) * 8);
      acc[0][tt] = __builtin_amdgcn_mfma_f32_16x16x32_f16(a0, b, acc[0][tt], 0, 0, 0);
      acc[1][tt] = __builtin_amdgcn_mfma_f32_16x16x32_f16(a1, b, acc[1][tt], 0, 0, 0);
    }
  }

#pragma unroll
  for (int g = 0; g < 2; ++g)
#pragma unroll
    for (int r = 0; r < 4; ++r) {
      int mg = n0 + wave * 32 + g * 16 + lq * 4 + r;
      bool vld = mg < NNODE;
      float o[4], ssum = 0.f, s2 = 0.f;
#pragma unroll
      for (int t0 = 0; t0 < 4; ++t0) {
        int f = t0 * 16 + l15;
        float rpre = acc[g][t0][r] + bsum[f];
        float zpre = acc[g][4 + t0][r] + bsum[64 + f];
        float ginv = acc[g][8 + t0][r] + bin_s[f];
        float ghnv = acc[g][12 + t0][r] + bhn_s[f];
        float rr = 1.f / (1.f + __expf(-rpre));
        float zz = 1.f / (1.f + __expf(-zpre));
        float hv = vld ? hid[(long)mg * 64 + f] : 0.f;
        float nn = tanhf(ginv + rr * ghnv);
        float oo = (1.f - zz) * nn + zz * hv;
        o[t0] = oo; ssum += oo; s2 += oo * oo;
      }
#pragma unroll
      for (int d = 1; d < 16; d <<= 1) {
        ssum += __shfl_xor(ssum, d);
        s2 += __shfl_xor(s2, d);
      }
      float mu = ssum * (1.f / 64.f);
      float var = s2 * (1.f / 64.f) - mu * mu;
      float rstd = rsqrtf(var + 1e-5f);
      if (vld)
#pragma unroll
        for (int t0 = 0; t0 < 4; ++t0) {
          int f = t0 * 16 + l15;
          out[(long)mg * 64 + f] = (o[t0] - mu) * rstd * gam_s[f] + bet_s[f];
        }
    }
}

extern "C" void kernel_launch(void* const* d_in, const int* in_sizes, int n_in,
                              void* d_out, int out_size, void* d_ws, size_t ws_size,
                              hipStream_t stream) {
  const float* node = (const float*)d_in[0];
  const float* edge = (const float*)d_in[1];
  const float* hid = (const float*)d_in[2];
  const int* src = (const int*)d_in[3];
  const int* dst = (const int*)d_in[4];
  const float* W1 = (const float*)d_in[5];
  const float* b1 = (const float*)d_in[6];
  const float* W2 = (const float*)d_in[7];
  const float* b2 = (const float*)d_in[8];
  const float* Wih = (const float*)d_in[9];
  const float* Whh = (const float*)d_in[10];
  const float* bih = (const float*)d_in[11];
  const float* bhh = (const float*)d_in[12];
  const float* gamma = (const float*)d_in[13];
  const float* beta = (const float*)d_in[14];

  char* ws = (char*)d_ws;
  f16* edgeh = (f16*)(ws + O_EDGEH);
  f16* w2g = (f16*)(ws + O_W2G);
  f16* b2g = (f16*)(ws + O_B2G);
  f16* w1g = (f16*)(ws + O_W1G);
  f16* wg = (f16*)(ws + O_WG);
  float* agg = (float*)(ws + O_AGG);

  k_prep<<<4542, 256, 0, stream>>>(edge, W1, W2, b2, Wih, Whh, edgeh, w1g, w2g, b2g, wg, agg);
  k_msg<<<1564, 256, 0, stream>>>(node, src, dst, edgeh, w1g, w2g, b1, agg);
  k_node<<<94, 256, 0, stream>>>(agg, hid, wg, bih, bhh, gamma, beta, (float*)d_out);
}